// Round 9
// baseline (193.669 us; speedup 1.0000x reference)
//
#include <hip/hip_runtime.h>
#include <math.h>

#define NS     512
#define NOBJ   16
#define MPTS   8192
#define HH     128
#define WW     128
#define HW     (HH * WW)
#define BLOCK  256
#define NWAVE  (BLOCK / 64)
#define SPLIT  4
#define CHUNK  (HW / SPLIT)                 // 4096 px per block
#define TILE   1024                         // px per staged tile
#define NTILE  (CHUNK / TILE)               // 4 tiles
#define SEG    (TILE / NWAVE)               // 256 px per wave
#define M_IT   (MPTS / SPLIT / (BLOCK * 4)) // 2 mesh groups per thread

typedef float f4 __attribute__((ext_vector_type(4)));
typedef int   i4 __attribute__((ext_vector_type(4)));

typedef const void __attribute__((address_space(1)))* gas1_t;
typedef void       __attribute__((address_space(3)))* las3_t;

__device__ __forceinline__ float frcp(float x)  { return __builtin_amdgcn_rcpf(x); }
__device__ __forceinline__ float fsqrt(float x) { return __builtin_amdgcn_sqrtf(x); }
__device__ __forceinline__ float rfl(float x) {
    return __int_as_float(__builtin_amdgcn_readfirstlane(__float_as_int(x)));
}
__device__ __forceinline__ void sched_fence() {
#if __has_builtin(__builtin_amdgcn_sched_barrier)
    __builtin_amdgcn_sched_barrier(0);
#endif
}
// gfx9 s_waitcnt simm16: vmcnt[3:0] (hi [15:14]), expcnt[6:4], lgkmcnt[11:8].
// Non-vm fields set to no-wait. n must be a literal <= 15 here.
#define WAIT_VM(n) __builtin_amdgcn_s_waitcnt((n) | (7 << 4) | (0xF << 8))

// Async global->LDS, 16 B per lane. LDS dest = wave-uniform base + lane*16.
__device__ __forceinline__ void dma16(const void* g, void* l) {
    __builtin_amdgcn_global_load_lds((gas1_t)g, (las3_t)l, 16, 0, 0);
}

__device__ __forceinline__ void fuse_proj(const float* __restrict__ cam_K,
                                          const float* __restrict__ R,
                                          const float* __restrict__ t, int n,
                                          float A[9], float b[3]) {
    float K[9], Rr[9], tt[3];
#pragma unroll
    for (int i = 0; i < 9; ++i) { K[i] = cam_K[n * 9 + i]; Rr[i] = R[n * 9 + i]; }
#pragma unroll
    for (int i = 0; i < 3; ++i) tt[i] = t[n * 3 + i];
#pragma unroll
    for (int r = 0; r < 3; ++r) {
#pragma unroll
        for (int c = 0; c < 3; ++c)
            A[r * 3 + c] = rfl(K[r * 3 + 0] * Rr[0 * 3 + c]
                             + K[r * 3 + 1] * Rr[1 * 3 + c]
                             + K[r * 3 + 2] * Rr[2 * 3 + c]);
        b[r] = rfl(K[r * 3 + 0] * tt[0] + K[r * 3 + 1] * tt[1] + K[r * 3 + 2] * tt[2]);
    }
}

// Stage one tile (4 arrays x 1 KB per wave) into LDS slot. All operands of the
// LDS base are wave-uniform; per-lane global ptr supplies the lane scatter.
__device__ __forceinline__ void stage_tile(const float* cx, const float* cy,
                                           const float* cz, const int* mk,
                                           float* lds, int slot, int gofs, int wofs) {
    float* base = lds + slot * (4 * TILE) + wofs;
    dma16(cx + gofs, base + 0 * TILE);
    dma16(cy + gofs, base + 1 * TILE);
    dma16(cz + gofs, base + 2 * TILE);
    dma16((const float*)mk + gofs, base + 3 * TILE);
}

__device__ __forceinline__ void compute_tile(const float* lds, int slot, int wofs,
                                             int lane, const float Ap[9],
                                             const float Ag[9], const float bp[3],
                                             const float bg[3],
                                             float& s_pv, float& s_m) {
    const float* base = lds + slot * (4 * TILE) + wofs + 4 * lane;
    const f4 vx = *(const f4*)(base + 0 * TILE);
    const f4 vy = *(const f4*)(base + 1 * TILE);
    const f4 vz = *(const f4*)(base + 2 * TILE);
    const i4 mm = *(const i4*)(base + 3 * TILE);
    const float xs[4] = {vx.x, vx.y, vx.z, vx.w};
    const float ys[4] = {vy.x, vy.y, vy.z, vy.w};
    const float zs[4] = {vz.x, vz.y, vz.z, vz.w};
    const int   ms[4] = {mm.x, mm.y, mm.z, mm.w};
#pragma unroll
    for (int j = 0; j < 4; ++j) {
        const float x = xs[j], y = ys[j], z = zs[j];
        const float hpx = fmaf(Ap[0], x, fmaf(Ap[1], y, fmaf(Ap[2], z, bp[0])));
        const float hpy = fmaf(Ap[3], x, fmaf(Ap[4], y, fmaf(Ap[5], z, bp[1])));
        const float hpz = fmaf(Ap[6], x, fmaf(Ap[7], y, fmaf(Ap[8], z, bp[2])));
        const float hgx = fmaf(Ag[0], x, fmaf(Ag[1], y, fmaf(Ag[2], z, bg[0])));
        const float hgy = fmaf(Ag[3], x, fmaf(Ag[4], y, fmaf(Ag[5], z, bg[1])));
        const float hgz = fmaf(Ag[6], x, fmaf(Ag[7], y, fmaf(Ag[8], z, bg[2])));
        const float iwp = frcp(hpz), iwg = frcp(hgz);
        const float du = fmaf(hpx, iwp, -hgx * iwg);
        const float dv = fmaf(hpy, iwp, -hgy * iwg);
        const float d  = fsqrt(fmaf(du, du, dv * dv));
        const float fm = (ms[j] != 0) ? 1.0f : 0.0f;
        s_pv += d * fm;
        s_m  += fm;
    }
}

__global__ __launch_bounds__(BLOCK) void score_partial(
    const int*   __restrict__ obj_id,
    const float* __restrict__ cam_K,
    const float* __restrict__ gt_R,
    const float* __restrict__ gt_t,
    const float* __restrict__ pr_R,
    const float* __restrict__ pr_t,
    const float* __restrict__ coord,      // [N,3,H,W]
    const int*   __restrict__ mask,       // [N,1,H,W]
    const float* __restrict__ mesh,       // [NOBJ,M,3]
    float*       __restrict__ ws)         // [N,SPLIT,4] : ad, pj, pv, m
{
    __shared__ float lds[4 * 4 * TILE];   // 64 KB: [slot][array][TILE]
    __shared__ float red[4][NWAVE];

    const int b    = blockIdx.x;
    const int n    = b >> 2;
    const int c    = b & (SPLIT - 1);
    const int tid  = threadIdx.x;
    const int w    = tid >> 6;
    const int lane = tid & 63;
    const int wofs = w * SEG;

    // ---- constants -> SGPR (scalar path) ----
    float Ap[9], Ag[9], bp[3], bg[3], dR[9], dt[3];
    fuse_proj(cam_K, pr_R, pr_t, n, Ap, bp);
    fuse_proj(cam_K, gt_R, gt_t, n, Ag, bg);
#pragma unroll
    for (int i = 0; i < 9; ++i) dR[i] = rfl(pr_R[n * 9 + i] - gt_R[n * 9 + i]);
#pragma unroll
    for (int i = 0; i < 3; ++i) dt[i] = rfl(pr_t[n * 3 + i] - gt_t[n * 3 + i]);
    const int obj = __builtin_amdgcn_readfirstlane(obj_id[n]);

    // ---- issue all pixel DMAs (4 tiles x 4 arrays = 16 per wave) ----
    const float* cx = coord + (size_t)n * 3 * HW;
    const float* cy = cx + HW;
    const float* cz = cx + 2 * HW;
    const int*   mk = mask + (size_t)n * HW;
    const int chunkBase = c * CHUNK;
    const int laneofs   = wofs + 4 * lane;

    stage_tile(cx, cy, cz, mk, lds, 0, chunkBase + 0 * TILE + laneofs, wofs);
    stage_tile(cx, cy, cz, mk, lds, 1, chunkBase + 1 * TILE + laneofs, wofs);
    stage_tile(cx, cy, cz, mk, lds, 2, chunkBase + 2 * TILE + laneofs, wofs);
    stage_tile(cx, cy, cz, mk, lds, 3, chunkBase + 3 * TILE + laneofs, wofs);

    // ---- mesh loads on the VGPR path (L2/L3-warm, small) ----
    const f4* mp4 = (const f4*)(mesh + (size_t)obj * MPTS * 3);
    f4 MF[M_IT][3];
#pragma unroll
    for (int it = 0; it < M_IT; ++it) {
        const int k = c * (MPTS / SPLIT / 4) + it * BLOCK + tid;
        MF[it][0] = mp4[k * 3 + 0];
        MF[it][1] = mp4[k * 3 + 1];
        MF[it][2] = mp4[k * 3 + 2];
    }
    sched_fence();

    // ---- pixel pipeline: vmcnt-rolled, wave-private (no __syncthreads) ----
    // Conservative wait constants valid whether the 6 mesh loads age before or
    // after the 16 DMAs: tile t consumable at vmcnt <= 12 - 4t.
    float s_pv = 0.0f, s_m = 0.0f;
    WAIT_VM(12); sched_fence();
    compute_tile(lds, 0, wofs, lane, Ap, Ag, bp, bg, s_pv, s_m);
    WAIT_VM(8);  sched_fence();
    compute_tile(lds, 1, wofs, lane, Ap, Ag, bp, bg, s_pv, s_m);
    WAIT_VM(4);  sched_fence();
    compute_tile(lds, 2, wofs, lane, Ap, Ag, bp, bg, s_pv, s_m);
    WAIT_VM(0);  sched_fence();
    compute_tile(lds, 3, wofs, lane, Ap, Ag, bp, bg, s_pv, s_m);

    // ---- mesh compute (all loads drained by WAIT_VM(0)) ----
    float s_ad = 0.0f, s_pj = 0.0f;
#pragma unroll
    for (int it = 0; it < M_IT; ++it) {
        const f4 f0 = MF[it][0], f1 = MF[it][1], f2 = MF[it][2];
        const float px[4] = {f0.x, f0.w, f1.z, f2.y};
        const float py[4] = {f0.y, f1.x, f1.w, f2.z};
        const float pz[4] = {f0.z, f1.y, f2.x, f2.w};
#pragma unroll
        for (int j = 0; j < 4; ++j) {
            const float x = px[j], y = py[j], z = pz[j];
            const float dx = fmaf(dR[0], x, fmaf(dR[1], y, fmaf(dR[2], z, dt[0])));
            const float dy = fmaf(dR[3], x, fmaf(dR[4], y, fmaf(dR[5], z, dt[1])));
            const float dz = fmaf(dR[6], x, fmaf(dR[7], y, fmaf(dR[8], z, dt[2])));
            s_ad += fsqrt(fmaf(dx, dx, fmaf(dy, dy, dz * dz)));
            const float hpx = fmaf(Ap[0], x, fmaf(Ap[1], y, fmaf(Ap[2], z, bp[0])));
            const float hpy = fmaf(Ap[3], x, fmaf(Ap[4], y, fmaf(Ap[5], z, bp[1])));
            const float hpz = fmaf(Ap[6], x, fmaf(Ap[7], y, fmaf(Ap[8], z, bp[2])));
            const float hgx = fmaf(Ag[0], x, fmaf(Ag[1], y, fmaf(Ag[2], z, bg[0])));
            const float hgy = fmaf(Ag[3], x, fmaf(Ag[4], y, fmaf(Ag[5], z, bg[1])));
            const float hgz = fmaf(Ag[6], x, fmaf(Ag[7], y, fmaf(Ag[8], z, bg[2])));
            const float iwp = frcp(hpz), iwg = frcp(hgz);
            const float du = fmaf(hpx, iwp, -hgx * iwg);
            const float dv = fmaf(hpy, iwp, -hgy * iwg);
            s_pj += fsqrt(fmaf(du, du, dv * dv));
        }
    }

    // ---- block reduction of 4 sums ----
    float vals[4] = {s_ad, s_pj, s_pv, s_m};
#pragma unroll
    for (int k = 0; k < 4; ++k)
#pragma unroll
        for (int off = 32; off > 0; off >>= 1)
            vals[k] += __shfl_down(vals[k], off, 64);

    if (lane == 0) {
#pragma unroll
        for (int k = 0; k < 4; ++k) red[k][w] = vals[k];
    }
    __syncthreads();
    if (tid == 0) {
#pragma unroll
        for (int k = 0; k < 4; ++k) {
            float s = 0.0f;
#pragma unroll
            for (int wv = 0; wv < NWAVE; ++wv) s += red[k][wv];
            ws[(size_t)(n * SPLIT + c) * 4 + k] = s;
        }
    }
}

// ---------------- final reduce + re/te ----------------
__global__ __launch_bounds__(256) void score_reduce(
    const float* __restrict__ ws,
    const int*   __restrict__ obj_id,
    const float* __restrict__ gt_R,
    const float* __restrict__ gt_t,
    const float* __restrict__ pr_R,
    const float* __restrict__ pr_t,
    const float* __restrict__ diam,
    float*       __restrict__ out)
{
    const int n = blockIdx.x * blockDim.x + threadIdx.x;
    if (n >= NS) return;

    float ad = 0.0f, pj = 0.0f, pv = 0.0f, m = 0.0f;
#pragma unroll
    for (int cb = 0; cb < SPLIT; ++cb) {
        const float* p = ws + (size_t)(n * SPLIT + cb) * 4;
        ad += p[0]; pj += p[1]; pv += p[2]; m += p[3];
    }

    float trace = 0.0f;
#pragma unroll
    for (int i = 0; i < 9; ++i) trace += pr_R[n * 9 + i] * gt_R[n * 9 + i];
    trace = fminf(fmaxf(trace, -1.0f), 3.0f);
    const float dx = pr_t[n * 3 + 0] - gt_t[n * 3 + 0];
    const float dy = pr_t[n * 3 + 1] - gt_t[n * 3 + 1];
    const float dz = pr_t[n * 3 + 2] - gt_t[n * 3 + 2];

    const float dia = diam[obj_id[n]];
    out[0 * NS + n] = acosf((trace - 1.0f) * 0.5f) * (180.0f / 3.14159265358979323846f);
    out[1 * NS + n] = sqrtf(dx * dx + dy * dy + dz * dz) * 100.0f;
    out[2 * NS + n] = ad * (1.0f / MPTS) / dia;
    out[3 * NS + n] = pj * (1.0f / MPTS);
    out[4 * NS + n] = pv / fmaxf(m, 1.0f);
}

extern "C" void kernel_launch(void* const* d_in, const int* in_sizes, int n_in,
                              void* d_out, int out_size, void* d_ws, size_t ws_size,
                              hipStream_t stream) {
    const int*   obj_id = (const int*)  d_in[0];
    const float* cam_K  = (const float*)d_in[1];
    const float* gt_R   = (const float*)d_in[2];
    const float* gt_t   = (const float*)d_in[3];
    const float* pr_R   = (const float*)d_in[4];
    const float* pr_t   = (const float*)d_in[5];
    const float* coord  = (const float*)d_in[6];
    const int*   mask   = (const int*)  d_in[7];
    const float* mesh   = (const float*)d_in[8];
    const float* diam   = (const float*)d_in[9];
    float* out = (float*)d_out;
    float* ws  = (float*)d_ws;   // N*SPLIT*4 floats = 32 KB

    score_partial<<<NS * SPLIT, BLOCK, 0, stream>>>(obj_id, cam_K, gt_R, gt_t, pr_R,
                                                    pr_t, coord, mask, mesh, ws);
    score_reduce<<<(NS + 255) / 256, 256, 0, stream>>>(ws, obj_id, gt_R, gt_t,
                                                       pr_R, pr_t, diam, out);
}

// Round 10
// 182.907 us; speedup vs baseline: 1.0588x; 1.0588x over previous
//
#include <hip/hip_runtime.h>
#include <math.h>

#define NS    512
#define NOBJ  16
#define MPTS  8192
#define HH    128
#define WW    128
#define HW    (HH * WW)
#define BLOCK 512
#define NWAVE (BLOCK / 64)
#define WSPAN (HW / NWAVE)          // 2048 contiguous px per wave
#define GRP   256                   // px per dwordx4 wave-instruction
#define STG   2                     // insts per array per stage (2-KB runs)
#define NSTG  (WSPAN / (GRP * STG)) // 4 stages per wave
#define M_IT  (MPTS / 4 / BLOCK)    // 4 mesh groups per thread

typedef float f4 __attribute__((ext_vector_type(4)));
typedef int   i4 __attribute__((ext_vector_type(4)));

__device__ __forceinline__ float frcp(float x)  { return __builtin_amdgcn_rcpf(x); }
__device__ __forceinline__ float fsqrt(float x) { return __builtin_amdgcn_sqrtf(x); }
__device__ __forceinline__ float rfl(float x) {
    return __int_as_float(__builtin_amdgcn_readfirstlane(__float_as_int(x)));
}
__device__ __forceinline__ void sched_fence() {
#if __has_builtin(__builtin_amdgcn_sched_barrier)
    __builtin_amdgcn_sched_barrier(0);
#endif
}
__device__ __forceinline__ f4 ntl_f4(const f4* p) {
#if __has_builtin(__builtin_nontemporal_load)
    return __builtin_nontemporal_load(p);
#else
    return *p;
#endif
}
__device__ __forceinline__ i4 ntl_i4(const i4* p) {
#if __has_builtin(__builtin_nontemporal_load)
    return __builtin_nontemporal_load(p);
#else
    return *p;
#endif
}

__device__ __forceinline__ void fuse_proj(const float* __restrict__ cam_K,
                                          const float* __restrict__ R,
                                          const float* __restrict__ t, int n,
                                          float A[9], float b[3]) {
    float K[9], Rr[9], tt[3];
#pragma unroll
    for (int i = 0; i < 9; ++i) { K[i] = cam_K[n * 9 + i]; Rr[i] = R[n * 9 + i]; }
#pragma unroll
    for (int i = 0; i < 3; ++i) tt[i] = t[n * 3 + i];
#pragma unroll
    for (int r = 0; r < 3; ++r) {
#pragma unroll
        for (int c = 0; c < 3; ++c)
            A[r * 3 + c] = rfl(K[r * 3 + 0] * Rr[0 * 3 + c]
                             + K[r * 3 + 1] * Rr[1 * 3 + c]
                             + K[r * 3 + 2] * Rr[2 * 3 + c]);
        b[r] = rfl(K[r * 3 + 0] * tt[0] + K[r * 3 + 1] * tt[1] + K[r * 3 + 2] * tt[2]);
    }
}

// One block per sample; each WAVE owns a contiguous 2048-px span so its four
// address streams (cx,cy,cz,mask) are strictly sequential (2-KB bursts), vs
// the previous tile*BLOCK+tid mapping (1-KB runs with 8-KB strides). Tests the
// hypothesis that the ~2.5 TB/s plateau is miss-service (row-locality) bound.
__global__ __attribute__((amdgpu_flat_work_group_size(BLOCK, BLOCK),
                          amdgpu_waves_per_eu(4, 4)))
void score_kernel(
    const int*   __restrict__ obj_id,
    const float* __restrict__ cam_K,
    const float* __restrict__ gt_R,
    const float* __restrict__ gt_t,
    const float* __restrict__ pr_R,
    const float* __restrict__ pr_t,
    const float* __restrict__ coord,      // [N,3,H,W]
    const int*   __restrict__ mask,       // [N,1,H,W]
    const float* __restrict__ mesh,       // [NOBJ,M,3]
    const float* __restrict__ diam,
    float*       __restrict__ out)        // [5*N]
{
    const int n    = blockIdx.x;
    const int tid  = threadIdx.x;
    const int w    = tid >> 6;
    const int lane = tid & 63;

    // ---- constants -> SGPR ----
    float Ap[9], Ag[9], bp[3], bg[3], dR[9], dt[3];
    fuse_proj(cam_K, pr_R, pr_t, n, Ap, bp);
    fuse_proj(cam_K, gt_R, gt_t, n, Ag, bg);
#pragma unroll
    for (int i = 0; i < 9; ++i) dR[i] = rfl(pr_R[n * 9 + i] - gt_R[n * 9 + i]);
#pragma unroll
    for (int i = 0; i < 3; ++i) dt[i] = rfl(pr_t[n * 3 + i] - gt_t[n * 3 + i]);
    const int obj = __builtin_amdgcn_readfirstlane(obj_id[n]);

    const float* cx = coord + (size_t)n * 3 * HW;
    const float* cy = cx + HW;
    const float* cz = cx + 2 * HW;
    const int*   mk = mask + (size_t)n * HW;
    const int wbase = w * WSPAN + 4 * lane;   // wave-sequential base

    // ---- pixel phase: depth-2 slot rotation over 4 stages ----
    f4 X[2][STG], Y[2][STG], Z[2][STG];
    i4 Mq[2][STG];

#define LOAD_STAGE(s, b)                                                     \
    {                                                                        \
        _Pragma("unroll")                                                    \
        for (int g = 0; g < STG; ++g) {                                      \
            const int p = wbase + (s) * (STG * GRP) + g * GRP;               \
            X[b][g]  = ntl_f4((const f4*)(cx + p));                          \
            Y[b][g]  = ntl_f4((const f4*)(cy + p));                          \
            Z[b][g]  = ntl_f4((const f4*)(cz + p));                          \
            Mq[b][g] = ntl_i4((const i4*)(mk + p));                          \
        }                                                                    \
    }

    LOAD_STAGE(0, 0)
    LOAD_STAGE(1, 1)
    sched_fence();

    float s_pv = 0.0f, s_m = 0.0f;
#pragma unroll
    for (int s = 0; s < NSTG; ++s) {
        const int b = s & 1;
#pragma unroll
        for (int g = 0; g < STG; ++g) {
            const float xs[4] = {X[b][g].x, X[b][g].y, X[b][g].z, X[b][g].w};
            const float ys[4] = {Y[b][g].x, Y[b][g].y, Y[b][g].z, Y[b][g].w};
            const float zs[4] = {Z[b][g].x, Z[b][g].y, Z[b][g].z, Z[b][g].w};
            const int   ms[4] = {Mq[b][g].x, Mq[b][g].y, Mq[b][g].z, Mq[b][g].w};
#pragma unroll
            for (int j = 0; j < 4; ++j) {
                const float x = xs[j], y = ys[j], z = zs[j];
                const float hpx = fmaf(Ap[0], x, fmaf(Ap[1], y, fmaf(Ap[2], z, bp[0])));
                const float hpy = fmaf(Ap[3], x, fmaf(Ap[4], y, fmaf(Ap[5], z, bp[1])));
                const float hpz = fmaf(Ap[6], x, fmaf(Ap[7], y, fmaf(Ap[8], z, bp[2])));
                const float hgx = fmaf(Ag[0], x, fmaf(Ag[1], y, fmaf(Ag[2], z, bg[0])));
                const float hgy = fmaf(Ag[3], x, fmaf(Ag[4], y, fmaf(Ag[5], z, bg[1])));
                const float hgz = fmaf(Ag[6], x, fmaf(Ag[7], y, fmaf(Ag[8], z, bg[2])));
                const float iwp = frcp(hpz), iwg = frcp(hgz);
                const float du = fmaf(hpx, iwp, -hgx * iwg);
                const float dv = fmaf(hpy, iwp, -hgy * iwg);
                const float d  = fsqrt(fmaf(du, du, dv * dv));
                const float fm = (ms[j] != 0) ? 1.0f : 0.0f;
                s_pv += d * fm;
                s_m  += fm;
            }
        }
        if (s + 2 < NSTG) {
            LOAD_STAGE(s + 2, b)      // refill freed slot; stream stays sequential
            sched_fence();
        }
    }

    // ---- mesh phase: batch issue, consume (L2/L3-warm) ----
    const f4* mp4 = (const f4*)(mesh + (size_t)obj * MPTS * 3);
    f4 MF[M_IT][3];
#pragma unroll
    for (int it = 0; it < M_IT; ++it) {
        const int k = it * BLOCK + tid;
        MF[it][0] = mp4[k * 3 + 0];
        MF[it][1] = mp4[k * 3 + 1];
        MF[it][2] = mp4[k * 3 + 2];
    }
    sched_fence();

    float s_ad = 0.0f, s_pj = 0.0f;
#pragma unroll
    for (int it = 0; it < M_IT; ++it) {
        const f4 f0 = MF[it][0], f1 = MF[it][1], f2 = MF[it][2];
        const float px[4] = {f0.x, f0.w, f1.z, f2.y};
        const float py[4] = {f0.y, f1.x, f1.w, f2.z};
        const float pz[4] = {f0.z, f1.y, f2.x, f2.w};
#pragma unroll
        for (int j = 0; j < 4; ++j) {
            const float x = px[j], y = py[j], z = pz[j];
            const float dx = fmaf(dR[0], x, fmaf(dR[1], y, fmaf(dR[2], z, dt[0])));
            const float dy = fmaf(dR[3], x, fmaf(dR[4], y, fmaf(dR[5], z, dt[1])));
            const float dz = fmaf(dR[6], x, fmaf(dR[7], y, fmaf(dR[8], z, dt[2])));
            s_ad += fsqrt(fmaf(dx, dx, fmaf(dy, dy, dz * dz)));
            const float hpx = fmaf(Ap[0], x, fmaf(Ap[1], y, fmaf(Ap[2], z, bp[0])));
            const float hpy = fmaf(Ap[3], x, fmaf(Ap[4], y, fmaf(Ap[5], z, bp[1])));
            const float hpz = fmaf(Ap[6], x, fmaf(Ap[7], y, fmaf(Ap[8], z, bp[2])));
            const float hgx = fmaf(Ag[0], x, fmaf(Ag[1], y, fmaf(Ag[2], z, bg[0])));
            const float hgy = fmaf(Ag[3], x, fmaf(Ag[4], y, fmaf(Ag[5], z, bg[1])));
            const float hgz = fmaf(Ag[6], x, fmaf(Ag[7], y, fmaf(Ag[8], z, bg[2])));
            const float iwp = frcp(hpz), iwg = frcp(hgz);
            const float du = fmaf(hpx, iwp, -hgx * iwg);
            const float dv = fmaf(hpy, iwp, -hgy * iwg);
            s_pj += fsqrt(fmaf(du, du, dv * dv));
        }
    }

    // ---- block reduction ----
    float vals[4] = {s_ad, s_pj, s_pv, s_m};
#pragma unroll
    for (int k = 0; k < 4; ++k)
#pragma unroll
        for (int off = 32; off > 0; off >>= 1)
            vals[k] += __shfl_down(vals[k], off, 64);

    __shared__ float red[4][NWAVE];
    if (lane == 0) {
#pragma unroll
        for (int k = 0; k < 4; ++k) red[k][w] = vals[k];
    }
    __syncthreads();

    if (tid == 0) {
        float tot[4];
#pragma unroll
        for (int k = 0; k < 4; ++k) {
            float s = 0.0f;
#pragma unroll
            for (int wv = 0; wv < NWAVE; ++wv) s += red[k][wv];
            tot[k] = s;
        }
        float Rg9[9], Rp9[9];
#pragma unroll
        for (int i = 0; i < 9; ++i) { Rg9[i] = gt_R[n * 9 + i]; Rp9[i] = pr_R[n * 9 + i]; }
        float trace = 0.0f;
#pragma unroll
        for (int i = 0; i < 9; ++i) trace += Rp9[i] * Rg9[i];
        trace = fminf(fmaxf(trace, -1.0f), 3.0f);
        const float te = sqrtf(dt[0] * dt[0] + dt[1] * dt[1] + dt[2] * dt[2]) * 100.0f;

        out[0 * NS + n] = acosf((trace - 1.0f) * 0.5f) * (180.0f / 3.14159265358979323846f);
        out[1 * NS + n] = te;
        out[2 * NS + n] = tot[0] * (1.0f / MPTS) / diam[obj];
        out[3 * NS + n] = tot[1] * (1.0f / MPTS);
        out[4 * NS + n] = tot[2] / fmaxf(tot[3], 1.0f);
    }
}

extern "C" void kernel_launch(void* const* d_in, const int* in_sizes, int n_in,
                              void* d_out, int out_size, void* d_ws, size_t ws_size,
                              hipStream_t stream) {
    const int*   obj_id = (const int*)  d_in[0];
    const float* cam_K  = (const float*)d_in[1];
    const float* gt_R   = (const float*)d_in[2];
    const float* gt_t   = (const float*)d_in[3];
    const float* pr_R   = (const float*)d_in[4];
    const float* pr_t   = (const float*)d_in[5];
    const float* coord  = (const float*)d_in[6];
    const int*   mask   = (const int*)  d_in[7];
    const float* mesh   = (const float*)d_in[8];
    const float* diam   = (const float*)d_in[9];
    float* out = (float*)d_out;

    score_kernel<<<NS, BLOCK, 0, stream>>>(obj_id, cam_K, gt_R, gt_t, pr_R, pr_t,
                                           coord, mask, mesh, diam, out);
}